// Round 11
// baseline (1372.814 us; speedup 1.0000x reference)
//
#include <hip/hip_runtime.h>

typedef unsigned short u16;
typedef unsigned int   u32;

typedef __attribute__((ext_vector_type(8))) short bf16x8;   // 8 bf16 (4 VGPRs)
typedef __attribute__((ext_vector_type(4))) float f32x4;

#define TB_TOTAL 98304   // T*B = 96*1024

// ---- f32 weight offsets inside ws (floats), base 16 (ws[0]=dtype flag) ----
#define OFF_WFI 16
#define OFF_BFI 528
#define OFF_WZ 560
#define OFF_UZ 4656
#define OFF_WR 8752
#define OFF_UR 12848
#define OFF_WH 16944
#define OFF_UH 21040
#define OFF_BZ 25136
#define OFF_BR 25264
#define OFF_BH 25392
#define OFF_WGP 25520
#define OFF_BGP 107440
#define OFF_WGCAT 107696
#define OFF_BGCAT 304304
#define OFF_W1 305072
#define OFF_B1 321456
#define OFF_W2 321520
#define OFF_B2 321584
#define WF_TOTAL 321569

// ---- byte offsets in ws ----
#define UGPK_BYTE  1286400ULL     // GARU U frag-packed (393216 B)
#define BPK2_BYTE  1679616ULL     // packed Wgp frags (163840 B)
#define BPK3_BYTE  1843456ULL     // packed Wgcat frags (393216 B)
#define GNNPK_BYTE 2236672ULL     // GNN frag pack (51200 B)
#define COMB_BYTE  2287872ULL     // bf16 [98304][320] (62914560 B)
#define AA_BYTE    65202432ULL    // bf16 [98304][768] (150994944 B)
// total ws usage ≈ 206 MiB

__device__ __forceinline__ float bf2f(u16 v) {
  return __uint_as_float(((u32)v) << 16);
}
__device__ __forceinline__ u16 f2bf(float f) {
  u32 x = __float_as_uint(f);
  u32 r = (x + 0x7FFFu + ((x >> 16) & 1u)) >> 16;
  return (u16)r;
}
__device__ __forceinline__ float sigm(float x) { return 1.f / (1.f + __expf(-x)); }
__device__ __forceinline__ float tanh_(float x) {
  x = fminf(fmaxf(x, -30.f), 30.f);
  float e = __expf(-2.f * x);
  return (1.f - e) / (1.f + e);
}
__device__ __forceinline__ float rdw(const void* p, int idx, bool bf) {
  return bf ? bf2f(((const u16*)p)[idx]) : ((const float*)p)[idx];
}

// ============================ D: dtype detector ============================
__global__ void k_detect(const u32* __restrict__ xbits, float* __restrict__ wsf) {
  __shared__ int cnt;
  if (threadIdx.x == 0) cnt = 0;
  __syncthreads();
  int good = 0;
  for (int i = 0; i < 64; i++) {
    u32 d = xbits[threadIdx.x * 64 + i];
    u32 e = (d >> 7) & 0xFFu;
    good += (e >= 100u && e <= 140u) ? 1 : 0;
  }
  atomicAdd(&cnt, good);
  __syncthreads();
  if (threadIdx.x == 0) wsf[0] = (cnt >= 8192) ? 1.0f : 0.0f;  // 1 = bf16 inputs
}

// ============================ K0: weight convert/reorg -> f32 ============================
__global__ void k_convert(
    const void* s_wfi, const void* s_bfi,
    const void* s_wz, const void* s_uz, const void* s_bz,
    const void* s_wr, const void* s_ur, const void* s_br,
    const void* s_wh, const void* s_uh, const void* s_bh,
    const void* s_wgp, const void* s_bgp,
    const void* s_wgz, const void* s_bgz,
    const void* s_wgr, const void* s_bgr,
    const void* s_wgn, const void* s_bgn,
    const void* s_w1, const void* s_b1,
    const void* s_w2, const void* s_b2,
    float* __restrict__ dst)
{
  int i = blockIdx.x * 256 + threadIdx.x;
  if (i >= WF_TOTAL) return;
  bool bf = dst[0] != 0.0f;
  int o = i;
  float v;
  if (o < 512) v = rdw(s_wfi, o, bf);
  else if ((o -= 512) < 32) v = rdw(s_bfi, o, bf);
  else if ((o -= 32) < 4096) v = rdw(s_wz, o, bf);
  else if ((o -= 4096) < 4096) v = rdw(s_uz, o, bf);
  else if ((o -= 4096) < 4096) v = rdw(s_wr, o, bf);
  else if ((o -= 4096) < 4096) v = rdw(s_ur, o, bf);
  else if ((o -= 4096) < 4096) v = rdw(s_wh, o, bf);
  else if ((o -= 4096) < 4096) v = rdw(s_uh, o, bf);
  else if ((o -= 4096) < 128) v = rdw(s_bz, o, bf);
  else if ((o -= 128) < 128) v = rdw(s_br, o, bf);
  else if ((o -= 128) < 128) v = rdw(s_bh, o, bf);
  else if ((o -= 128) < 81920) v = rdw(s_wgp, o, bf);
  else if ((o -= 81920) < 256) v = rdw(s_bgp, o, bf);
  else if ((o -= 256) < 196608) {      // wgcat [256][768] = [Wgz|Wgr|Wgn]
    int c = o / 768; int col = o - c * 768;
    int sel = col >> 8; int g = col & 255;
    const void* s = (sel == 0) ? s_wgz : (sel == 1) ? s_wgr : s_wgn;
    v = rdw(s, c * 256 + g, bf);
  }
  else if ((o -= 196608) < 768) {      // bgcat
    int sel = o >> 8; int g = o & 255;
    const void* s = (sel == 0) ? s_bgz : (sel == 1) ? s_bgr : s_bgn;
    v = rdw(s, g, bf);
  }
  else if ((o -= 768) < 16384) v = rdw(s_w1, o, bf);
  else if ((o -= 16384) < 64) v = rdw(s_b1, o, bf);
  else if ((o -= 64) < 64) v = rdw(s_w2, o, bf);
  else v = rdw(s_b2, 0, bf);
  dst[16 + i] = v;
}

// K0b: pack GARU U-matrices into MFMA B-fragment order [3][16cb][8kb][64][8]
__global__ void k_pack_ug(const void* s_ugz, const void* s_ugr, const void* s_ugn,
                          const float* __restrict__ wsf, u16* __restrict__ dst) {
  int i = blockIdx.x * 256 + threadIdx.x;
  if (i >= 196608) return;
  bool bf = wsf[0] != 0.0f;
  int mat = i >> 16, ii = i & 65535;
  int chunk = ii >> 9;          // cb*8 + kb
  int rest = ii & 511;          // lane*8 + j
  int lane = rest >> 3, j = rest & 7;
  int cb = chunk >> 3, kb = chunk & 7;
  int k = kb * 32 + (lane >> 4) * 8 + j;
  int g = cb * 16 + (lane & 15);
  int src = k * 256 + g;
  const void* s = (mat == 0) ? s_ugz : (mat == 1) ? s_ugr : s_ugn;
  dst[i] = bf ? ((const u16*)s)[src] : f2bf(((const float*)s)[src]);
}

// K0c: pack Wgp / [Wgz|Wgr|Wgn] into MFMA B-fragment order
__global__ void k_pack(const void* s_wgp, const void* s_wgz, const void* s_wgr, const void* s_wgn,
                       const float* __restrict__ wsf, u16* __restrict__ bpk2, u16* __restrict__ bpk3) {
  int i = blockIdx.x * 256 + threadIdx.x;
  bool bf = wsf[0] != 0.0f;
  if (i < 81920) {                       // Wgp [320][256], ncb=16
    int chunk = i >> 9;
    int rest = i & 511;
    int lane = rest >> 3, j = rest & 7;
    int kb = chunk >> 4, cbg = chunk & 15;
    int k = kb * 32 + (lane >> 4) * 8 + j;
    int col = cbg * 16 + (lane & 15);
    int src = k * 256 + col;
    bpk2[i] = bf ? ((const u16*)s_wgp)[src] : f2bf(((const float*)s_wgp)[src]);
  } else if (i < 81920 + 196608) {       // Wgcat [256][768], ncb=48
    int ii = i - 81920;
    int chunk = ii >> 9;
    int rest = ii & 511;
    int lane = rest >> 3, j = rest & 7;
    int kb = chunk / 48, cbg = chunk % 48;
    int k = kb * 32 + (lane >> 4) * 8 + j;
    int col = cbg * 16 + (lane & 15);
    int sel = col >> 8, g = col & 255;
    const void* s = (sel == 0) ? s_wgz : (sel == 1) ? s_wgr : s_wgn;
    int src = k * 256 + g;
    bpk3[ii] = bf ? ((const u16*)s)[src] : f2bf(((const float*)s)[src]);
  }
}

// K0d: pack GNN layer matrices {Wz,Uz,Wr,Ur,Wh,Uh}[4] + Wfi into B-frag order
__global__ void k_pack_gnn(const void* s_wfi,
                           const void* s_wz, const void* s_uz,
                           const void* s_wr, const void* s_ur,
                           const void* s_wh, const void* s_uh,
                           const float* __restrict__ wsf, u16* __restrict__ dst) {
  int i = blockIdx.x * 256 + threadIdx.x;
  if (i >= 25600) return;
  bool bf = wsf[0] != 0.0f;
  if (i < 24576) {
    int l = i / 6144;
    int r1 = i - l * 6144;
    int mat = r1 >> 10;
    int r2 = r1 & 1023;
    int cb = r2 >> 9;
    int r3 = r2 & 511;
    int lane = r3 >> 3, j = r3 & 7;
    int k = (lane >> 4) * 8 + j;
    int col = cb * 16 + (lane & 15);
    const void* s = (mat == 0) ? s_wz : (mat == 1) ? s_uz : (mat == 2) ? s_wr
                  : (mat == 3) ? s_ur : (mat == 4) ? s_wh : s_uh;
    int src = l * 1024 + k * 32 + col;
    dst[i] = bf ? ((const u16*)s)[src] : f2bf(((const float*)s)[src]);
  } else {                                // Wfi [16][32] B-frags [2][64][8]
    int ii = i - 24576;
    int cb = ii >> 9;
    int r3 = ii & 511;
    int lane = r3 >> 3, j = r3 & 7;
    int k = (lane >> 4) * 8 + j;
    int col = cb * 16 + (lane & 15);
    dst[i] = (k < 16) ? (bf ? ((const u16*)s_wfi)[k * 32 + col]
                            : f2bf(((const float*)s_wfi)[k * 32 + col]))
                      : (u16)0;
  }
}

// ============================ K1: MFMA GNN stack v4 ============================
// 320 threads = 5 waves; 16 problems / 160 node-rows = 10 tiles; wave w owns
// tiles {w, 5+w} — perfectly balanced. 50 KB LDS -> 3 blocks/CU (15 waves).
#define GP 16
#define LDST 40    // u16 stride per row (80 B)
__global__ __launch_bounds__(320, 3) void k_gnn_mfma(
    const void* __restrict__ xv, const void* __restrict__ adjv,
    const float* __restrict__ wsf, const u16* __restrict__ gnnpk,
    u16* __restrict__ comb)
{
  __shared__ u16 shn[160 * LDST];        // h rows bf16
  __shared__ u16 smm[160 * LDST];        // m rows / rh rows (shared)
  __shared__ u16 hbf[16 * 2 * 32 * 8];   // h B-frags, compact 32-lane
  __shared__ u16 adjf[16 * 32 * 8];      // adj A-frags, compact

  int tid = threadIdx.x;
  int w = tid >> 6, lane = tid & 63, quad = lane >> 4, l16 = lane & 15;
  bool isbf = wsf[0] != 0.0f;
  long base = (long)blockIdx.x * GP;

  const bf16x8 z8 = {0, 0, 0, 0, 0, 0, 0, 0};
  const f32x4 zf = {0.f, 0.f, 0.f, 0.f};

  {
    u32* hz = (u32*)hbf;
    for (int i = tid; i < 8192; i += 320) hz[i] = 0u;
    u32* az = (u32*)adjf;
    for (int i = tid; i < 2048; i += 320) az[i] = 0u;
  }
  __syncthreads();

  if (tid < 160) {
    int p = tid / 10, k = tid - p * 10;
    float ar[10];
    float deg = 0.f;
    if (isbf) {
      const u16* ap = (const u16*)adjv + (base + p) * 100 + k * 10;
#pragma unroll
      for (int i = 0; i < 10; i++) {
        float v = bf2f(ap[i]) + (i == k ? 1.f : 0.f);
        ar[i] = v; deg += v;
      }
    } else {
      const float* ap = (const float*)adjv + (base + p) * 100 + k * 10;
#pragma unroll
      for (int i = 0; i < 10; i++) {
        float v = ap[i] + (i == k ? 1.f : 0.f);
        ar[i] = v; deg += v;
      }
    }
    float inv = 1.f / (deg + 1e-6f);
#pragma unroll
    for (int i = 0; i < 10; i++)
      adjf[(p * 32 + ((i >> 3) << 4) + k) * 8 + (i & 7)] = f2bf(ar[i] * inv);
  }

  int tiles[2] = {w, 5 + w};

  int vr = 10 - quad * 4; vr = vr < 0 ? 0 : (vr > 4 ? 4 : vr);
  int aggb[4];
#pragma unroll
  for (int pp = 0; pp < 4; pp++)
    aggb[pp] = (((w & 3) * 4 + pp) * 10 + quad * 4) * LDST + l16;

  int rdA[2], wb[2], hbfa[2][4];
#pragma unroll
  for (int tt = 0; tt < 2; tt++) {
    int t = tiles[tt];
    rdA[tt] = (t * 16 + l16) * LDST + quad * 8;
    wb[tt]  = (t * 16 + quad * 4) * LDST + l16;
#pragma unroll
    for (int r = 0; r < 4; r++) {
      int g2 = t * 16 + quad * 4 + r;
      int p2 = (g2 * 205) >> 11;       // g2/10 for g2<160
      int nd = g2 - p2 * 10;
      hbfa[tt][r] = p2 * 512 + ((((nd >> 3) << 4) + l16) << 3) + (nd & 7);
    }
  }

  float bzv[4][2], brv[4][2], bhv[4][2];
#pragma unroll
  for (int l = 0; l < 4; l++)
#pragma unroll
    for (int cb = 0; cb < 2; cb++) {
      bzv[l][cb] = wsf[OFF_BZ + l * 32 + cb * 16 + l16];
      brv[l][cb] = wsf[OFF_BR + l * 32 + cb * 16 + l16];
      bhv[l][cb] = wsf[OFF_BH + l * 32 + cb * 16 + l16];
    }

  bf16x8 wfiF[2];
  wfiF[0] = *(const bf16x8*)(gnnpk + 24576 + (size_t)lane * 8);
  wfiF[1] = *(const bf16x8*)(gnnpk + 24576 + (size_t)(64 + lane) * 8);
  float bfi0 = wsf[OFF_BFI + l16];
  float bfi1 = wsf[OFF_BFI + 16 + l16];

  f32x4 h0C[2][2], hC[2][2];
#pragma unroll
  for (int tt = 0; tt < 2; tt++) {
    int t = tiles[tt];
    int grow = t * 16 + l16;
    bf16x8 xA = z8;
    if (quad < 2) {
      size_t xoff = ((size_t)(base * 10 + grow) << 4) + quad * 8;
      if (isbf) {
        xA = *(const bf16x8*)((const u16*)xv + xoff);
      } else {
        const float* xf = (const float*)xv + xoff;
        union { u16 e[8]; bf16x8 v; } ux;
#pragma unroll
        for (int j = 0; j < 8; j++) ux.e[j] = f2bf(xf[j]);
        xA = ux.v;
      }
    }
    f32x4 c0 = {bfi0, bfi0, bfi0, bfi0};
    f32x4 c1 = {bfi1, bfi1, bfi1, bfi1};
    h0C[tt][0] = __builtin_amdgcn_mfma_f32_16x16x32_bf16(xA, wfiF[0], c0, 0, 0, 0);
    h0C[tt][1] = __builtin_amdgcn_mfma_f32_16x16x32_bf16(xA, wfiF[1], c1, 0, 0, 0);
#pragma unroll
    for (int cb = 0; cb < 2; cb++) {
#pragma unroll
      for (int r = 0; r < 4; r++) {
        float hv = h0C[tt][cb][r];
        hC[tt][cb][r] = hv;
        u16 hb = f2bf(hv);
        shn[wb[tt] + r * LDST + cb * 16] = hb;
        hbf[hbfa[tt][r] + cb * 256] = hb;
      }
    }
  }
  __syncthreads();

#pragma unroll
  for (int l = 0; l < 4; l++) {
    bf16x8 Bf[6][2];
#pragma unroll
    for (int mat = 0; mat < 6; mat++)
#pragma unroll
      for (int cb = 0; cb < 2; cb++)
        Bf[mat][cb] = *(const bf16x8*)(gnnpk + (((l * 6 + mat) * 2 + cb) * 64 + lane) * 8);

    // P1: aggregation via MFMA (waves 0-3 own 4 problems each; wave 4 idle)
    if (w < 4) {
#pragma unroll
      for (int pp = 0; pp < 4; pp++) {
        int p = w * 4 + pp;
        bf16x8 aA = z8, hB0 = z8, hB1 = z8;
        if (lane < 32) {
          aA  = *(const bf16x8*)&adjf[(p * 32 + lane) * 8];
          hB0 = *(const bf16x8*)&hbf[((p * 2 + 0) * 32 + lane) * 8];
          hB1 = *(const bf16x8*)&hbf[((p * 2 + 1) * 32 + lane) * 8];
        }
        f32x4 m0 = __builtin_amdgcn_mfma_f32_16x16x32_bf16(aA, hB0, zf, 0, 0, 0);
        f32x4 m1 = __builtin_amdgcn_mfma_f32_16x16x32_bf16(aA, hB1, zf, 0, 0, 0);
#pragma unroll
        for (int r = 0; r < 4; r++) {
          if (r < vr) {
            smm[aggb[pp] + r * LDST] = f2bf(m0[r]);
            smm[aggb[pp] + r * LDST + 16] = f2bf(m1[r]);
          }
        }
      }
    }
    __syncthreads();

    // P2+P3 fused per tile (rh is wave-local); 2 tiles per wave, balanced
#pragma unroll
    for (int tt = 0; tt < 2; tt++) {
      bf16x8 mA = *(const bf16x8*)&smm[rdA[tt]];
      bf16x8 hA = *(const bf16x8*)&shn[rdA[tt]];
      f32x4 Cz[2], Cn[2];
#pragma unroll
      for (int cb = 0; cb < 2; cb++) {
        float bz = bzv[l][cb];
        float br = brv[l][cb];
        float bh = bhv[l][cb];
        f32x4 cz = {bz, bz, bz, bz};
        f32x4 cr = {br, br, br, br};
        f32x4 cn = {bh, bh, bh, bh};
        cz = __builtin_amdgcn_mfma_f32_16x16x32_bf16(mA, Bf[0][cb], cz, 0, 0, 0);
        cz = __builtin_amdgcn_mfma_f32_16x16x32_bf16(hA, Bf[1][cb], cz, 0, 0, 0);
        cr = __builtin_amdgcn_mfma_f32_16x16x32_bf16(mA, Bf[2][cb], cr, 0, 0, 0);
        cr = __builtin_amdgcn_mfma_f32_16x16x32_bf16(hA, Bf[3][cb], cr, 0, 0, 0);
        cn = __builtin_amdgcn_mfma_f32_16x16x32_bf16(mA, Bf[4][cb], cn, 0, 0, 0);
#pragma unroll
        for (int r = 0; r < 4; r++) {
          float z = sigm(cz[r]);
          float rr = sigm(cr[r]);
          cz[r] = z;
          smm[wb[tt] + r * LDST + cb * 16] = f2bf(rr * hC[tt][cb][r]);
        }
        Cz[cb] = cz; Cn[cb] = cn;
      }
      bf16x8 rA = *(const bf16x8*)&smm[rdA[tt]];
#pragma unroll
      for (int cb = 0; cb < 2; cb++) {
        Cn[cb] = __builtin_amdgcn_mfma_f32_16x16x32_bf16(rA, Bf[5][cb], Cn[cb], 0, 0, 0);
#pragma unroll
        for (int r = 0; r < 4; r++) {
          float n = tanh_(Cn[cb][r]);
          float h = hC[tt][cb][r];
          h = fmaf(Cz[cb][r], n - h, h) + h0C[tt][cb][r];
          hC[tt][cb][r] = h;
          u16 hb = f2bf(h);
          shn[wb[tt] + r * LDST + cb * 16] = hb;
          hbf[hbfa[tt][r] + cb * 256] = hb;
        }
      }
    }
    __syncthreads();
  }

  if (tid < 160) {
    const uint4* src = (const uint4*)&shn[tid * LDST];
    uint4* dst = (uint4*)(comb + ((size_t)base * 10 + tid) * 32);
#pragma unroll
    for (int q4 = 0; q4 < 4; q4++) dst[q4] = src[q4];
  }
}

// ============================ K2+K3 fused: comb -> gi(LDS) -> aa ============================
__global__ __launch_bounds__(256, 2) void k_gemm_fused(
    const u16* __restrict__ comb, const u16* __restrict__ bpk2, const u16* __restrict__ bpk3,
    const float* __restrict__ wsf, u16* __restrict__ aa)
{
  __shared__ u16 gt[64 * 264];   // gi tile, row stride 264 u16

  int tid = threadIdx.x;
  int wv = tid >> 6, lane = tid & 63, quad = lane >> 4, l16 = lane & 15;
  long row0 = (long)blockIdx.x * 64;
  int lrow = wv * 16;

  const float* bgp = wsf + OFF_BGP;
  f32x4 acc[16];
#pragma unroll
  for (int cb = 0; cb < 16; cb++) {
    float b = bgp[cb * 16 + l16];
    acc[cb] = (f32x4){b, b, b, b};
  }
  const u16* arow = comb + (row0 + lrow + l16) * 320 + quad * 8;
  for (int kb = 0; kb < 10; kb++) {
    bf16x8 af = *(const bf16x8*)(arow + kb * 32);
    const u16* bbase = bpk2 + ((long)(kb * 16) * 64 + lane) * 8;
#pragma unroll
    for (int cb = 0; cb < 16; cb++) {
      bf16x8 bfv = *(const bf16x8*)(bbase + cb * 512);
      acc[cb] = __builtin_amdgcn_mfma_f32_16x16x32_bf16(af, bfv, acc[cb], 0, 0, 0);
    }
  }
#pragma unroll
  for (int cb = 0; cb < 16; cb++)
#pragma unroll
    for (int r = 0; r < 4; r++)
      gt[(lrow + quad * 4 + r) * 264 + cb * 16 + l16] = f2bf(acc[cb][r]);
  __syncthreads();

  const float* bgc = wsf + OFF_BGCAT;
  const u16* arow2 = &gt[(lrow + l16) * 264 + quad * 8];
  for (int cg = 0; cg < 3; cg++) {
    int col0 = cg << 8;
#pragma unroll
    for (int cb = 0; cb < 16; cb++) {
      float b = bgc[col0 + cb * 16 + l16];
      acc[cb] = (f32x4){b, b, b, b};
    }
    for (int kb = 0; kb < 8; kb++) {
      bf16x8 af = *(const bf16x8*)(arow2 + kb * 32);
      const u16* bbase = bpk3 + ((long)(kb * 48 + (col0 >> 4)) * 64 + lane) * 8;
#pragma unroll
      for (int cb = 0; cb < 16; cb++) {
        bf16x8 bfv = *(const bf16x8*)(bbase + cb * 512);
        acc[cb] = __builtin_amdgcn_mfma_f32_16x16x32_bf16(af, bfv, acc[cb], 0, 0, 0);
      }
    }
#pragma unroll
    for (int cb = 0; cb < 16; cb++)
#pragma unroll
      for (int r = 0; r < 4; r++) {
        long row = row0 + lrow + quad * 4 + r;
        aa[row * 768 + col0 + cb * 16 + l16] = f2bf(acc[cb][r]);
      }
  }
}

// ============================ K4: MFMA GARU v4 ============================
// fz/fr in VGPRs (128), Ugn in LDS; aa prefetch packed as u32 pairs (12/buf).
#define GARU_LOADP(ab, dz, dR, dn)                                           \
  {                                                                          \
    _Pragma("unroll")                                                        \
    for (int cb2 = 0; cb2 < 2; cb2++) {                                      \
      int col = c0 + cb2 * 16 + l16;                                         \
      _Pragma("unroll")                                                      \
      for (int h2 = 0; h2 < 2; h2++) {                                       \
        int rowa = quad * 4 + h2 * 2;                                        \
        u32 z0 = (ab)[rowa * 768 + col];                                     \
        u32 z1 = (ab)[(rowa + 1) * 768 + col];                               \
        dz[cb2 * 2 + h2] = z0 | (z1 << 16);                                  \
        u32 r0 = (ab)[rowa * 768 + 256 + col];                               \
        u32 r1 = (ab)[(rowa + 1) * 768 + 256 + col];                         \
        dR[cb2 * 2 + h2] = r0 | (r1 << 16);                                  \
        u32 n0 = (ab)[rowa * 768 + 512 + col];                               \
        u32 n1 = (ab)[(rowa + 1) * 768 + 512 + col];                         \
        dn[cb2 * 2 + h2] = n0 | (n1 << 16);                                  \
      }                                                                      \
    }                                                                        \
  }

#define UNPK(d, cb2, r) bf2f((u16)((d)[(cb2) * 2 + ((r) >> 1)] >> (((r) & 1) * 16)))

#define GARU_STEP(dz, dR, dn)                                                \
  {                                                                          \
    f32x4 uz0 = zero4, uz1 = zero4, ur0 = zero4, ur1 = zero4;                \
    _Pragma("unroll")                                                        \
    for (int kb = 0; kb < 8; kb++) {                                         \
      bf16x8 hA = *(const bf16x8*)(shA + kb * 512 + lane * 8);               \
      uz0 = __builtin_amdgcn_mfma_f32_16x16x32_bf16(hA, fz[0][kb], uz0, 0, 0, 0); \
      uz1 = __builtin_amdgcn_mfma_f32_16x16x32_bf16(hA, fz[1][kb], uz1, 0, 0, 0); \
      ur0 = __builtin_amdgcn_mfma_f32_16x16x32_bf16(hA, fr[0][kb], ur0, 0, 0, 0); \
      ur1 = __builtin_amdgcn_mfma_f32_16x16x32_bf16(hA, fr[1][kb], ur1, 0, 0, 0); \
    }                                                                        \
    _Pragma("unroll")                                                        \
    for (int r = 0; r < 4; r++) {                                            \
      float g0 = sigm(UNPK(dR, 0, r) + ur0[r]);                              \
      float g1 = sigm(UNPK(dR, 1, r) + ur1[r]);                              \
      srs[scat[0] + r * 8] = f2bf(g0 * hold[0][r]);                          \
      srs[scat[1] + r * 8] = f2bf(g1 * hold[1][r]);                          \
    }                                                                        \
    __syncthreads();                                                         \
    f32x4 un0 = zero4, un1 = zero4;                                          \
    _Pragma("unroll")                                                        \
    for (int kb = 0; kb < 8; kb++) {                                         \
      bf16x8 rA = *(const bf16x8*)(srs + kb * 512 + lane * 8);               \
      bf16x8 b0 = *(const bf16x8*)(pUgn0 + kb * 512);                        \
      bf16x8 b1 = *(const bf16x8*)(pUgn1 + kb * 512);                        \
      un0 = __builtin_amdgcn_mfma_f32_16x16x32_bf16(rA, b0, un0, 0, 0, 0);   \
      un1 = __builtin_amdgcn_mfma_f32_16x16x32_bf16(rA, b1, un1, 0, 0, 0);   \
    }                                                                        \
    _Pragma("unroll")                                                        \
    for (int r = 0; r < 4; r++) {                                            \
      float gz0 = sigm(UNPK(dz, 0, r) + uz0[r]);                             \
      float gz1 = sigm(UNPK(dz, 1, r) + uz1[r]);                             \
      float gn0 = tanh_(UNPK(dn, 0, r) + un0[r]);                            \
      float gn1 = tanh_(UNPK(dn, 1, r) + un1[r]);                            \
      float h0n = fmaf(gz0, hold[0][r] - gn0, gn0);                          \
      float h1n = fmaf(gz1, hold[1][r] - gn1, gn1);                          \
      hold[0][r] = h0n;                                                      \
      hold[1][r] = h1n;                                                      \
      shA[scat[0] + r * 8] = f2bf(h0n);                                      \
      shA[scat[1] + r * 8] = f2bf(h1n);                                      \
    }                                                                        \
    __syncthreads();                                                         \
  }

__global__ __launch_bounds__(512, 2) void k_garu_mfma(
    const u16* __restrict__ aa, const u16* __restrict__ ugpk,
    const float* __restrict__ wsf, float* __restrict__ outp)
{
  extern __shared__ u16 sm[];
  u16* sUgn = sm;                  // [16cb][8kb][64][8] (128 KB)
  u16* shA  = sm + 65536;          // h  A-frags [8kb][64][8]
  u16* srs  = sm + 65536 + 4096;   // rs A-frags

  int tid = threadIdx.x;
  int w = tid >> 6;
  int lane = tid & 63;
  int quad = lane >> 4;
  int l16 = lane & 15;
  int row0 = blockIdx.x * 16;
  int c0 = w * 32;
  int cbase = w * 2;

  {
    const uint4* src = (const uint4*)(ugpk + 2 * 65536);
    uint4* dst = (uint4*)sUgn;
    for (int d = tid; d < 8192; d += 512) dst[d] = src[d];
  }
  ((uint4*)shA)[tid] = (uint4){0u, 0u, 0u, 0u};

  bf16x8 fz[2][8], fr[2][8];
#pragma unroll
  for (int cb2 = 0; cb2 < 2; cb2++) {
#pragma unroll
    for (int kb = 0; kb < 8; kb++) {
      fz[cb2][kb] = *(const bf16x8*)(ugpk + ((((cbase + cb2)) * 8 + kb) * 64 + lane) * 8);
      fr[cb2][kb] = *(const bf16x8*)(ugpk + (((16 + cbase + cb2) * 8 + kb) * 64 + lane) * 8);
    }
  }

  // step-invariant Ugn LDS base pointers (kb stride = 512 u16 — one chunk)
  const u16* pUgn0 = sUgn + ((cbase + 0) * 8) * 512 + lane * 8;
  const u16* pUgn1 = sUgn + ((cbase + 1) * 8) * 512 + lane * 8;

  float hold[2][4];
#pragma unroll
  for (int cb2 = 0; cb2 < 2; cb2++)
#pragma unroll
    for (int r = 0; r < 4; r++) hold[cb2][r] = 0.f;

  int scat[2];
#pragma unroll
  for (int cb2 = 0; cb2 < 2; cb2++) {
    int col = c0 + cb2 * 16 + l16;
    scat[cb2] = (col >> 5) * 512 + ((col >> 3) & 3) * 128 + (quad * 4) * 8 + (col & 7);
  }

  const f32x4 zero4 = (f32x4){0.f, 0.f, 0.f, 0.f};
  u32 dzA[4], dRA[4], dnA[4], dzB[4], dRB[4], dnB[4];

  __syncthreads();

  GARU_LOADP(aa + (size_t)row0 * 768, dzA, dRA, dnA);   // st = 0

  for (int st2 = 0; st2 < 96; st2 += 2) {
    const u16* abB = aa + ((size_t)(st2 + 1) * 1024 + row0) * 768;
    GARU_LOADP(abB, dzB, dRB, dnB);
    GARU_STEP(dzA, dRA, dnA);
    if (st2 + 2 < 96) {
      const u16* abA = aa + ((size_t)(st2 + 2) * 1024 + row0) * 768;
      GARU_LOADP(abA, dzA, dRA, dnA);
    }
    GARU_STEP(dzB, dRB, dnB);
  }

  // classifier
  const float* W1 = wsf + OFF_W1;
  const float* B1 = wsf + OFF_B1;
  const float* W2 = wsf + OFF_W2;
  const float* B2 = wsf + OFF_B2;
#pragma unroll
  for (int rloc = 0; rloc < 2; rloc++) {
    int rr = w * 2 + rloc;
    float hid = B1[lane];
    for (int c = 0; c < 256; c++) {
      int addr = (c >> 5) * 512 + ((c >> 3) & 3) * 128 + rr * 8 + (c & 7);
      hid = fmaf(bf2f(shA[addr]), W1[c * 64 + lane], hid);
    }
    hid = fmaxf(hid, 0.f);
    float v = hid * W2[lane];
#pragma unroll
    for (int off = 32; off > 0; off >>= 1) v += __shfl_xor(v, off, 64);
    if (lane == 0) outp[row0 + rr] = sigm(v + B2[0]);
  }
}

// ============================ launch ============================
extern "C" void kernel_launch(void* const* d_in, const int* in_sizes, int n_in,
                              void* d_out, int out_size, void* d_ws, size_t ws_size,
                              hipStream_t stream) {
  const void* x    = d_in[0];
  const void* adj  = d_in[1];
  const void* wfi  = d_in[2];
  const void* wz   = d_in[4];
  const void* uz   = d_in[5];
  const void* bz   = d_in[6];
  const void* wr   = d_in[7];
  const void* ur   = d_in[8];
  const void* br   = d_in[9];
  const void* wh   = d_in[10];
  const void* uh   = d_in[11];
  const void* bh   = d_in[12];
  const void* wgp  = d_in[13];
  const void* bgp  = d_in[14];
  const void* wgz  = d_in[15];
  const void* ugz  = d_in[16];
  const void* bgz  = d_in[17];
  const void* wgr  = d_in[18];
  const void* ugr  = d_in[19];
  const void* bgr  = d_in[20];
  const void* wgn  = d_in[21];
  const void* ugn  = d_in[22];
  const void* bgn  = d_in[23];

  float* wsf  = (float*)d_ws;
  u16* ugpk   = (u16*)((char*)d_ws + UGPK_BYTE);
  u16* bpk2   = (u16*)((char*)d_ws + BPK2_BYTE);
  u16* bpk3   = (u16*)((char*)d_ws + BPK3_BYTE);
  u16* gnnpk  = (u16*)((char*)d_ws + GNNPK_BYTE);
  u16* comb   = (u16*)((char*)d_ws + COMB_BYTE);
  u16* aa     = (u16*)((char*)d_ws + AA_BYTE);

  k_detect<<<1, 256, 0, stream>>>((const u32*)x, wsf);

  k_convert<<<(WF_TOTAL + 255) / 256, 256, 0, stream>>>(
      wfi, d_in[3], wz, uz, bz, wr, ur, br, wh, uh, bh,
      wgp, bgp, wgz, bgz, wgr, bgr, wgn, bgn, d_in[24], d_in[25], d_in[26], d_in[27], wsf);

  k_pack_ug<<<(196608 + 255) / 256, 256, 0, stream>>>(ugz, ugr, ugn, wsf, ugpk);

  k_pack<<<(81920 + 196608 + 255) / 256, 256, 0, stream>>>(
      wgp, wgz, wgr, wgn, wsf, bpk2, bpk3);

  k_pack_gnn<<<100, 256, 0, stream>>>(wfi, wz, uz, wr, ur, wh, uh, wsf, gnnpk);

  // K1: all 98304 problems -> comb (320-thread balanced blocks)
  k_gnn_mfma<<<TB_TOTAL / GP, 320, 0, stream>>>(x, adj, wsf, gnnpk, comb);

  // K2+K3 fused: comb -> (gi in LDS) -> aa
  k_gemm_fused<<<TB_TOTAL / 64, 256, 0, stream>>>(comb, bpk2, bpk3, wsf, aa);

  // K4: MFMA GARU v4 -> d_out (144 KB dynamic LDS)
  k_garu_mfma<<<64, 512, 147456, stream>>>(aa, ugpk, wsf, (float*)d_out);
}

// Round 12
// 1007.569 us; speedup vs baseline: 1.3625x; 1.3625x over previous
//
#include <hip/hip_runtime.h>

typedef unsigned short u16;
typedef unsigned int   u32;

typedef __attribute__((ext_vector_type(8))) short bf16x8;   // 8 bf16 (4 VGPRs)
typedef __attribute__((ext_vector_type(4))) float f32x4;

#define TB_TOTAL 98304   // T*B = 96*1024

// ---- f32 weight offsets inside ws (floats), base 16 (ws[0]=dtype flag) ----
#define OFF_WFI 16
#define OFF_BFI 528
#define OFF_WZ 560
#define OFF_UZ 4656
#define OFF_WR 8752
#define OFF_UR 12848
#define OFF_WH 16944
#define OFF_UH 21040
#define OFF_BZ 25136
#define OFF_BR 25264
#define OFF_BH 25392
#define OFF_WGP 25520
#define OFF_BGP 107440
#define OFF_WGCAT 107696
#define OFF_BGCAT 304304
#define OFF_W1 305072
#define OFF_B1 321456
#define OFF_W2 321520
#define OFF_B2 321584
#define WF_TOTAL 321569

// ---- byte offsets in ws (R4-style aliasing: gi separate, aa overwrites dead comb) ----
#define UGPK_BYTE  1286400ULL     // GARU U frag-packed (393216 B)
#define BPK2_BYTE  1679616ULL     // packed Wgp frags (163840 B)
#define BPK3_BYTE  1843456ULL     // packed Wgcat frags (393216 B)
#define GNNPK_BYTE 2236672ULL     // GNN frag pack (51200 B)
#define GI_BYTE    2287872ULL     // bf16 [98304][256] (50331648 B)
#define X_BYTE     52619520ULL    // COMB [98304][320] then AA [98304][768] (aliased)
// total ws usage ≈ 203.6 MiB (R1 evidence: >=254 MiB available)

__device__ __forceinline__ float bf2f(u16 v) {
  return __uint_as_float(((u32)v) << 16);
}
__device__ __forceinline__ u16 f2bf(float f) {
  u32 x = __float_as_uint(f);
  u32 r = (x + 0x7FFFu + ((x >> 16) & 1u)) >> 16;
  return (u16)r;
}
__device__ __forceinline__ float sigm(float x) { return 1.f / (1.f + __expf(-x)); }
__device__ __forceinline__ float tanh_(float x) {
  x = fminf(fmaxf(x, -30.f), 30.f);
  float e = __expf(-2.f * x);
  return (1.f - e) / (1.f + e);
}
__device__ __forceinline__ float rdw(const void* p, int idx, bool bf) {
  return bf ? bf2f(((const u16*)p)[idx]) : ((const float*)p)[idx];
}

// ============================ D: dtype detector ============================
__global__ void k_detect(const u32* __restrict__ xbits, float* __restrict__ wsf) {
  __shared__ int cnt;
  if (threadIdx.x == 0) cnt = 0;
  __syncthreads();
  int good = 0;
  for (int i = 0; i < 64; i++) {
    u32 d = xbits[threadIdx.x * 64 + i];
    u32 e = (d >> 7) & 0xFFu;
    good += (e >= 100u && e <= 140u) ? 1 : 0;
  }
  atomicAdd(&cnt, good);
  __syncthreads();
  if (threadIdx.x == 0) wsf[0] = (cnt >= 8192) ? 1.0f : 0.0f;  // 1 = bf16 inputs
}

// ============================ K0: weight convert/reorg -> f32 ============================
__global__ void k_convert(
    const void* s_wfi, const void* s_bfi,
    const void* s_wz, const void* s_uz, const void* s_bz,
    const void* s_wr, const void* s_ur, const void* s_br,
    const void* s_wh, const void* s_uh, const void* s_bh,
    const void* s_wgp, const void* s_bgp,
    const void* s_wgz, const void* s_bgz,
    const void* s_wgr, const void* s_bgr,
    const void* s_wgn, const void* s_bgn,
    const void* s_w1, const void* s_b1,
    const void* s_w2, const void* s_b2,
    float* __restrict__ dst)
{
  int i = blockIdx.x * 256 + threadIdx.x;
  if (i >= WF_TOTAL) return;
  bool bf = dst[0] != 0.0f;
  int o = i;
  float v;
  if (o < 512) v = rdw(s_wfi, o, bf);
  else if ((o -= 512) < 32) v = rdw(s_bfi, o, bf);
  else if ((o -= 32) < 4096) v = rdw(s_wz, o, bf);
  else if ((o -= 4096) < 4096) v = rdw(s_uz, o, bf);
  else if ((o -= 4096) < 4096) v = rdw(s_wr, o, bf);
  else if ((o -= 4096) < 4096) v = rdw(s_ur, o, bf);
  else if ((o -= 4096) < 4096) v = rdw(s_wh, o, bf);
  else if ((o -= 4096) < 4096) v = rdw(s_uh, o, bf);
  else if ((o -= 4096) < 128) v = rdw(s_bz, o, bf);
  else if ((o -= 128) < 128) v = rdw(s_br, o, bf);
  else if ((o -= 128) < 128) v = rdw(s_bh, o, bf);
  else if ((o -= 128) < 81920) v = rdw(s_wgp, o, bf);
  else if ((o -= 81920) < 256) v = rdw(s_bgp, o, bf);
  else if ((o -= 256) < 196608) {      // wgcat [256][768] = [Wgz|Wgr|Wgn]
    int c = o / 768; int col = o - c * 768;
    int sel = col >> 8; int g = col & 255;
    const void* s = (sel == 0) ? s_wgz : (sel == 1) ? s_wgr : s_wgn;
    v = rdw(s, c * 256 + g, bf);
  }
  else if ((o -= 196608) < 768) {      // bgcat
    int sel = o >> 8; int g = o & 255;
    const void* s = (sel == 0) ? s_bgz : (sel == 1) ? s_bgr : s_bgn;
    v = rdw(s, g, bf);
  }
  else if ((o -= 768) < 16384) v = rdw(s_w1, o, bf);
  else if ((o -= 16384) < 64) v = rdw(s_b1, o, bf);
  else if ((o -= 64) < 64) v = rdw(s_w2, o, bf);
  else v = rdw(s_b2, 0, bf);
  dst[16 + i] = v;
}

// K0b: pack GARU U-matrices into MFMA B-fragment order [3][16cb][8kb][64][8]
__global__ void k_pack_ug(const void* s_ugz, const void* s_ugr, const void* s_ugn,
                          const float* __restrict__ wsf, u16* __restrict__ dst) {
  int i = blockIdx.x * 256 + threadIdx.x;
  if (i >= 196608) return;
  bool bf = wsf[0] != 0.0f;
  int mat = i >> 16, ii = i & 65535;
  int chunk = ii >> 9;          // cb*8 + kb
  int rest = ii & 511;          // lane*8 + j
  int lane = rest >> 3, j = rest & 7;
  int cb = chunk >> 3, kb = chunk & 7;
  int k = kb * 32 + (lane >> 4) * 8 + j;
  int g = cb * 16 + (lane & 15);
  int src = k * 256 + g;
  const void* s = (mat == 0) ? s_ugz : (mat == 1) ? s_ugr : s_ugn;
  dst[i] = bf ? ((const u16*)s)[src] : f2bf(((const float*)s)[src]);
}

// K0c: pack Wgp / [Wgz|Wgr|Wgn] into MFMA B-fragment order
__global__ void k_pack(const void* s_wgp, const void* s_wgz, const void* s_wgr, const void* s_wgn,
                       const float* __restrict__ wsf, u16* __restrict__ bpk2, u16* __restrict__ bpk3) {
  int i = blockIdx.x * 256 + threadIdx.x;
  bool bf = wsf[0] != 0.0f;
  if (i < 81920) {                       // Wgp [320][256], ncb=16
    int chunk = i >> 9;
    int rest = i & 511;
    int lane = rest >> 3, j = rest & 7;
    int kb = chunk >> 4, cbg = chunk & 15;
    int k = kb * 32 + (lane >> 4) * 8 + j;
    int col = cbg * 16 + (lane & 15);
    int src = k * 256 + col;
    bpk2[i] = bf ? ((const u16*)s_wgp)[src] : f2bf(((const float*)s_wgp)[src]);
  } else if (i < 81920 + 196608) {       // Wgcat [256][768], ncb=48
    int ii = i - 81920;
    int chunk = ii >> 9;
    int rest = ii & 511;
    int lane = rest >> 3, j = rest & 7;
    int kb = chunk / 48, cbg = chunk % 48;
    int k = kb * 32 + (lane >> 4) * 8 + j;
    int col = cbg * 16 + (lane & 15);
    int sel = col >> 8, g = col & 255;
    const void* s = (sel == 0) ? s_wgz : (sel == 1) ? s_wgr : s_wgn;
    int src = k * 256 + g;
    bpk3[ii] = bf ? ((const u16*)s)[src] : f2bf(((const float*)s)[src]);
  }
}

// K0d: pack GNN layer matrices {Wz,Uz,Wr,Ur,Wh,Uh}[4] + Wfi into B-frag order
__global__ void k_pack_gnn(const void* s_wfi,
                           const void* s_wz, const void* s_uz,
                           const void* s_wr, const void* s_ur,
                           const void* s_wh, const void* s_uh,
                           const float* __restrict__ wsf, u16* __restrict__ dst) {
  int i = blockIdx.x * 256 + threadIdx.x;
  if (i >= 25600) return;
  bool bf = wsf[0] != 0.0f;
  if (i < 24576) {
    int l = i / 6144;
    int r1 = i - l * 6144;
    int mat = r1 >> 10;
    int r2 = r1 & 1023;
    int cb = r2 >> 9;
    int r3 = r2 & 511;
    int lane = r3 >> 3, j = r3 & 7;
    int k = (lane >> 4) * 8 + j;
    int col = cb * 16 + (lane & 15);
    const void* s = (mat == 0) ? s_wz : (mat == 1) ? s_uz : (mat == 2) ? s_wr
                  : (mat == 3) ? s_ur : (mat == 4) ? s_wh : s_uh;
    int src = l * 1024 + k * 32 + col;
    dst[i] = bf ? ((const u16*)s)[src] : f2bf(((const float*)s)[src]);
  } else {                                // Wfi [16][32] B-frags [2][64][8]
    int ii = i - 24576;
    int cb = ii >> 9;
    int r3 = ii & 511;
    int lane = r3 >> 3, j = r3 & 7;
    int k = (lane >> 4) * 8 + j;
    int col = cb * 16 + (lane & 15);
    dst[i] = (k < 16) ? (bf ? ((const u16*)s_wfi)[k * 32 + col]
                            : f2bf(((const float*)s_wfi)[k * 32 + col]))
                      : (u16)0;
  }
}

// ============================ K1: MFMA GNN stack v3 (R10 known-good: 380 us) ============================
#define GP 16
#define LDST 40    // u16 stride per row (80 B)
__global__ __launch_bounds__(256, 2) void k_gnn_mfma(
    const void* __restrict__ xv, const void* __restrict__ adjv,
    const float* __restrict__ wsf, const u16* __restrict__ gnnpk,
    u16* __restrict__ comb)
{
  __shared__ u16 shn[160 * LDST];        // h rows bf16
  __shared__ u16 smm[160 * LDST];        // m rows / rh rows (shared)
  __shared__ u16 hbf[16 * 2 * 32 * 8];   // h B-frags, compact 32-lane
  __shared__ u16 adjf[16 * 32 * 8];      // adj A-frags, compact

  int tid = threadIdx.x;
  int w = tid >> 6, lane = tid & 63, quad = lane >> 4, l16 = lane & 15;
  bool isbf = wsf[0] != 0.0f;
  long base = (long)blockIdx.x * GP;

  const bf16x8 z8 = {0, 0, 0, 0, 0, 0, 0, 0};
  const f32x4 zf = {0.f, 0.f, 0.f, 0.f};

  {
    u32* hz = (u32*)hbf;
#pragma unroll
    for (int i = 0; i < 32; i++) hz[tid + 256 * i] = 0u;
    u32* az = (u32*)adjf;
#pragma unroll
    for (int i = 0; i < 8; i++) az[tid + 256 * i] = 0u;
  }
  __syncthreads();

  if (tid < 160) {
    int p = tid / 10, k = tid - p * 10;
    float ar[10];
    float deg = 0.f;
    if (isbf) {
      const u16* ap = (const u16*)adjv + (base + p) * 100 + k * 10;
#pragma unroll
      for (int i = 0; i < 10; i++) {
        float v = bf2f(ap[i]) + (i == k ? 1.f : 0.f);
        ar[i] = v; deg += v;
      }
    } else {
      const float* ap = (const float*)adjv + (base + p) * 100 + k * 10;
#pragma unroll
      for (int i = 0; i < 10; i++) {
        float v = ap[i] + (i == k ? 1.f : 0.f);
        ar[i] = v; deg += v;
      }
    }
    float inv = 1.f / (deg + 1e-6f);
#pragma unroll
    for (int i = 0; i < 10; i++)
      adjf[(p * 32 + ((i >> 3) << 4) + k) * 8 + (i & 7)] = f2bf(ar[i] * inv);
  }

  int ntile = (w < 2) ? 3 : 2;
  int tiles[3] = {w, 4 + w, 8 + w};

  int vr = 10 - quad * 4; vr = vr < 0 ? 0 : (vr > 4 ? 4 : vr);
  int aggb[4];
#pragma unroll
  for (int pp = 0; pp < 4; pp++)
    aggb[pp] = ((w * 4 + pp) * 10 + quad * 4) * LDST + l16;

  int rdA[3], wb[3], hbfa[3][4];
#pragma unroll
  for (int tt = 0; tt < 3; tt++) {
    int t = tiles[tt];
    rdA[tt] = (t * 16 + l16) * LDST + quad * 8;
    wb[tt]  = (t * 16 + quad * 4) * LDST + l16;
#pragma unroll
    for (int r = 0; r < 4; r++) {
      int g2 = t * 16 + quad * 4 + r;
      int p2 = (g2 * 205) >> 11;
      int nd = g2 - p2 * 10;
      hbfa[tt][r] = p2 * 512 + ((((nd >> 3) << 4) + l16) << 3) + (nd & 7);
    }
  }

  float bzv[4][2], brv[4][2], bhv[4][2];
#pragma unroll
  for (int l = 0; l < 4; l++)
#pragma unroll
    for (int cb = 0; cb < 2; cb++) {
      bzv[l][cb] = wsf[OFF_BZ + l * 32 + cb * 16 + l16];
      brv[l][cb] = wsf[OFF_BR + l * 32 + cb * 16 + l16];
      bhv[l][cb] = wsf[OFF_BH + l * 32 + cb * 16 + l16];
    }

  bf16x8 wfiF[2];
  wfiF[0] = *(const bf16x8*)(gnnpk + 24576 + (size_t)lane * 8);
  wfiF[1] = *(const bf16x8*)(gnnpk + 24576 + (size_t)(64 + lane) * 8);
  float bfi0 = wsf[OFF_BFI + l16];
  float bfi1 = wsf[OFF_BFI + 16 + l16];

  f32x4 h0C[3][2], hC[3][2];
#pragma unroll
  for (int tt = 0; tt < 3; tt++) {
    if (tt < ntile) {
      int t = tiles[tt];
      int grow = t * 16 + l16;
      bf16x8 xA = z8;
      if (quad < 2) {
        size_t xoff = ((size_t)(base * 10 + grow) << 4) + quad * 8;
        if (isbf) {
          xA = *(const bf16x8*)((const u16*)xv + xoff);
        } else {
          const float* xf = (const float*)xv + xoff;
          union { u16 e[8]; bf16x8 v; } ux;
#pragma unroll
          for (int j = 0; j < 8; j++) ux.e[j] = f2bf(xf[j]);
          xA = ux.v;
        }
      }
      f32x4 c0 = {bfi0, bfi0, bfi0, bfi0};
      f32x4 c1 = {bfi1, bfi1, bfi1, bfi1};
      h0C[tt][0] = __builtin_amdgcn_mfma_f32_16x16x32_bf16(xA, wfiF[0], c0, 0, 0, 0);
      h0C[tt][1] = __builtin_amdgcn_mfma_f32_16x16x32_bf16(xA, wfiF[1], c1, 0, 0, 0);
#pragma unroll
      for (int cb = 0; cb < 2; cb++) {
#pragma unroll
        for (int r = 0; r < 4; r++) {
          float hv = h0C[tt][cb][r];
          hC[tt][cb][r] = hv;
          u16 hb = f2bf(hv);
          shn[wb[tt] + r * LDST + cb * 16] = hb;
          hbf[hbfa[tt][r] + cb * 256] = hb;
        }
      }
    }
  }
  __syncthreads();

#pragma unroll
  for (int l = 0; l < 4; l++) {
    bf16x8 Bf[6][2];
#pragma unroll
    for (int mat = 0; mat < 6; mat++)
#pragma unroll
      for (int cb = 0; cb < 2; cb++)
        Bf[mat][cb] = *(const bf16x8*)(gnnpk + (((l * 6 + mat) * 2 + cb) * 64 + lane) * 8);

#pragma unroll
    for (int pp = 0; pp < 4; pp++) {
      int p = w * 4 + pp;
      bf16x8 aA = z8, hB0 = z8, hB1 = z8;
      if (lane < 32) {
        aA  = *(const bf16x8*)&adjf[(p * 32 + lane) * 8];
        hB0 = *(const bf16x8*)&hbf[((p * 2 + 0) * 32 + lane) * 8];
        hB1 = *(const bf16x8*)&hbf[((p * 2 + 1) * 32 + lane) * 8];
      }
      f32x4 m0 = __builtin_amdgcn_mfma_f32_16x16x32_bf16(aA, hB0, zf, 0, 0, 0);
      f32x4 m1 = __builtin_amdgcn_mfma_f32_16x16x32_bf16(aA, hB1, zf, 0, 0, 0);
#pragma unroll
      for (int r = 0; r < 4; r++) {
        if (r < vr) {
          smm[aggb[pp] + r * LDST] = f2bf(m0[r]);
          smm[aggb[pp] + r * LDST + 16] = f2bf(m1[r]);
        }
      }
    }
    __syncthreads();

#pragma unroll
    for (int tt = 0; tt < 3; tt++) {
      if (tt < ntile) {
        bf16x8 mA = *(const bf16x8*)&smm[rdA[tt]];
        bf16x8 hA = *(const bf16x8*)&shn[rdA[tt]];
        f32x4 Cz[2], Cn[2];
#pragma unroll
        for (int cb = 0; cb < 2; cb++) {
          float bz = bzv[l][cb];
          float br = brv[l][cb];
          float bh = bhv[l][cb];
          f32x4 cz = {bz, bz, bz, bz};
          f32x4 cr = {br, br, br, br};
          f32x4 cn = {bh, bh, bh, bh};
          cz = __builtin_amdgcn_mfma_f32_16x16x32_bf16(mA, Bf[0][cb], cz, 0, 0, 0);
          cz = __builtin_amdgcn_mfma_f32_16x16x32_bf16(hA, Bf[1][cb], cz, 0, 0, 0);
          cr = __builtin_amdgcn_mfma_f32_16x16x32_bf16(mA, Bf[2][cb], cr, 0, 0, 0);
          cr = __builtin_amdgcn_mfma_f32_16x16x32_bf16(hA, Bf[3][cb], cr, 0, 0, 0);
          cn = __builtin_amdgcn_mfma_f32_16x16x32_bf16(mA, Bf[4][cb], cn, 0, 0, 0);
#pragma unroll
          for (int r = 0; r < 4; r++) {
            float z = sigm(cz[r]);
            float rr = sigm(cr[r]);
            cz[r] = z;
            smm[wb[tt] + r * LDST + cb * 16] = f2bf(rr * hC[tt][cb][r]);
          }
          Cz[cb] = cz; Cn[cb] = cn;
        }
        bf16x8 rA = *(const bf16x8*)&smm[rdA[tt]];
#pragma unroll
        for (int cb = 0; cb < 2; cb++) {
          Cn[cb] = __builtin_amdgcn_mfma_f32_16x16x32_bf16(rA, Bf[5][cb], Cn[cb], 0, 0, 0);
#pragma unroll
          for (int r = 0; r < 4; r++) {
            float n = tanh_(Cn[cb][r]);
            float h = hC[tt][cb][r];
            h = fmaf(Cz[cb][r], n - h, h) + h0C[tt][cb][r];
            hC[tt][cb][r] = h;
            u16 hb = f2bf(h);
            shn[wb[tt] + r * LDST + cb * 16] = hb;
            hbf[hbfa[tt][r] + cb * 256] = hb;
          }
        }
      }
    }
    __syncthreads();
  }

  if (tid < 160) {
    const uint4* src = (const uint4*)&shn[tid * LDST];
    uint4* dst = (uint4*)(comb + ((size_t)base * 10 + tid) * 32);
#pragma unroll
    for (int q4 = 0; q4 < 4; q4++) dst[q4] = src[q4];
  }
}

// ============================ K2/K3: separate MFMA GEMM (R4 known-good: ~75 us total) ============================
__global__ __launch_bounds__(256, 2) void k_gemm_mfma(
    const u16* __restrict__ in, const u16* __restrict__ bpk,
    const float* __restrict__ bias, u16* __restrict__ out,
    int K, int N)
{
  int tid = threadIdx.x;
  int wv = tid >> 6;
  int lane = tid & 63;
  int quad = lane >> 4;
  int l16 = lane & 15;
  long row0 = (long)blockIdx.x * 64 + wv * 16;
  int col0 = blockIdx.y << 8;
  int ncb = N >> 4;
  int nk = K >> 5;

  f32x4 acc[16];
#pragma unroll
  for (int cb = 0; cb < 16; cb++) {
    float b = bias[col0 + cb * 16 + l16];
    acc[cb] = (f32x4){b, b, b, b};
  }

  const u16* arow = in + (row0 + l16) * K + quad * 8;
  for (int kb = 0; kb < nk; kb++) {
    bf16x8 af = *(const bf16x8*)(arow + kb * 32);
    const u16* bbase = bpk + ((long)(kb * ncb + (col0 >> 4)) * 64 + lane) * 8;
#pragma unroll
    for (int cb = 0; cb < 16; cb++) {
      bf16x8 bfv = *(const bf16x8*)(bbase + cb * 512);
      acc[cb] = __builtin_amdgcn_mfma_f32_16x16x32_bf16(af, bfv, acc[cb], 0, 0, 0);
    }
  }

#pragma unroll
  for (int cb = 0; cb < 16; cb++) {
#pragma unroll
    for (int r = 0; r < 4; r++) {
      long row = row0 + quad * 4 + r;
      out[row * N + col0 + cb * 16 + l16] = f2bf(acc[cb][r]);
    }
  }
}

// ============================ K4: MFMA GARU v4 (packed aa prefetch) ============================
#define GARU_LOADP(ab, dz, dR, dn)                                           \
  {                                                                          \
    _Pragma("unroll")                                                        \
    for (int cb2 = 0; cb2 < 2; cb2++) {                                      \
      int col = c0 + cb2 * 16 + l16;                                         \
      _Pragma("unroll")                                                      \
      for (int h2 = 0; h2 < 2; h2++) {                                       \
        int rowa = quad * 4 + h2 * 2;                                        \
        u32 z0 = (ab)[rowa * 768 + col];                                     \
        u32 z1 = (ab)[(rowa + 1) * 768 + col];                               \
        dz[cb2 * 2 + h2] = z0 | (z1 << 16);                                  \
        u32 r0 = (ab)[rowa * 768 + 256 + col];                               \
        u32 r1 = (ab)[(rowa + 1) * 768 + 256 + col];                         \
        dR[cb2 * 2 + h2] = r0 | (r1 << 16);                                  \
        u32 n0 = (ab)[rowa * 768 + 512 + col];                               \
        u32 n1 = (ab)[(rowa + 1) * 768 + 512 + col];                         \
        dn[cb2 * 2 + h2] = n0 | (n1 << 16);                                  \
      }                                                                      \
    }                                                                        \
  }

#define UNPK(d, cb2, r) bf2f((u16)((d)[(cb2) * 2 + ((r) >> 1)] >> (((r) & 1) * 16)))

#define GARU_STEP(dz, dR, dn)                                                \
  {                                                                          \
    f32x4 uz0 = zero4, uz1 = zero4, ur0 = zero4, ur1 = zero4;                \
    _Pragma("unroll")                                                        \
    for (int kb = 0; kb < 8; kb++) {                                         \
      bf16x8 hA = *(const bf16x8*)(shA + kb * 512 + lane * 8);               \
      uz0 = __builtin_amdgcn_mfma_f32_16x16x32_bf16(hA, fz[0][kb], uz0, 0, 0, 0); \
      uz1 = __builtin_amdgcn_mfma_f32_16x16x32_bf16(hA, fz[1][kb], uz1, 0, 0, 0); \
      ur0 = __builtin_amdgcn_mfma_f32_16x16x32_bf16(hA, fr[0][kb], ur0, 0, 0, 0); \
      ur1 = __builtin_amdgcn_mfma_f32_16x16x32_bf16(hA, fr[1][kb], ur1, 0, 0, 0); \
    }                                                                        \
    _Pragma("unroll")                                                        \
    for (int r = 0; r < 4; r++) {                                            \
      float g0 = sigm(UNPK(dR, 0, r) + ur0[r]);                              \
      float g1 = sigm(UNPK(dR, 1, r) + ur1[r]);                              \
      srs[scat[0] + r * 8] = f2bf(g0 * hold[0][r]);                          \
      srs[scat[1] + r * 8] = f2bf(g1 * hold[1][r]);                          \
    }                                                                        \
    __syncthreads();                                                         \
    f32x4 un0 = zero4, un1 = zero4;                                          \
    _Pragma("unroll")                                                        \
    for (int kb = 0; kb < 8; kb++) {                                         \
      bf16x8 rA = *(const bf16x8*)(srs + kb * 512 + lane * 8);               \
      bf16x8 b0 = *(const bf16x8*)(pUgn0 + kb * 512);                        \
      bf16x8 b1 = *(const bf16x8*)(pUgn1 + kb * 512);                        \
      un0 = __builtin_amdgcn_mfma_f32_16x16x32_bf16(rA, b0, un0, 0, 0, 0);   \
      un1 = __builtin_amdgcn_mfma_f32_16x16x32_bf16(rA, b1, un1, 0, 0, 0);   \
    }                                                                        \
    _Pragma("unroll")                                                        \
    for (int r = 0; r < 4; r++) {                                            \
      float gz0 = sigm(UNPK(dz, 0, r) + uz0[r]);                             \
      float gz1 = sigm(UNPK(dz, 1, r) + uz1[r]);                             \
      float gn0 = tanh_(UNPK(dn, 0, r) + un0[r]);                            \
      float gn1 = tanh_(UNPK(dn, 1, r) + un1[r]);                            \
      float h0n = fmaf(gz0, hold[0][r] - gn0, gn0);                          \
      float h1n = fmaf(gz1, hold[1][r] - gn1, gn1);                          \
      hold[0][r] = h0n;                                                      \
      hold[1][r] = h1n;                                                      \
      shA[scat[0] + r * 8] = f2bf(h0n);                                      \
      shA[scat[1] + r * 8] = f2bf(h1n);                                      \
    }                                                                        \
    __syncthreads();                                                         \
  }

__global__ __launch_bounds__(512, 2) void k_garu_mfma(
    const u16* __restrict__ aa, const u16* __restrict__ ugpk,
    const float* __restrict__ wsf, float* __restrict__ outp)
{
  extern __shared__ u16 sm[];
  u16* sUgn = sm;                  // [16cb][8kb][64][8] (128 KB)
  u16* shA  = sm + 65536;          // h  A-frags [8kb][64][8]
  u16* srs  = sm + 65536 + 4096;   // rs A-frags

  int tid = threadIdx.x;
  int w = tid >> 6;
  int lane = tid & 63;
  int quad = lane >> 4;
  int l16 = lane & 15;
  int row0 = blockIdx.x * 16;
  int c0 = w * 32;
  int cbase = w * 2;

  {
    const uint4* src = (const uint4*)(ugpk + 2 * 65536);
    uint4* dst = (uint4*)sUgn;
    for (int d = tid; d < 8192; d += 512) dst[d] = src[d];
  }
  ((uint4*)shA)[tid] = (uint4){0u, 0u, 0u, 0u};

  bf16x8 fz[2][8], fr[2][8];
#pragma unroll
  for (int cb2 = 0; cb2 < 2; cb2++) {
#pragma unroll
    for (int kb = 0; kb < 8; kb++) {
      fz[cb2][kb] = *(const bf16x8*)(ugpk + ((((cbase + cb2)) * 8 + kb) * 64 + lane) * 8);
      fr[cb2][kb] = *(const bf16x8*)(ugpk + (((16 + cbase + cb2) * 8 + kb) * 64 + lane) * 8);
    }
  }

  const u16* pUgn0 = sUgn + ((cbase + 0) * 8) * 512 + lane * 8;
  const u16* pUgn1 = sUgn + ((cbase + 1) * 8) * 512 + lane * 8;

  float hold[2][4];
#pragma unroll
  for (int cb2 = 0; cb2 < 2; cb2++)
#pragma unroll
    for (int r = 0; r < 4; r++) hold[cb2][r] = 0.f;

  int scat[2];
#pragma unroll
  for (int cb2 = 0; cb2 < 2; cb2++) {
    int col = c0 + cb2 * 16 + l16;
    scat[cb2] = (col >> 5) * 512 + ((col >> 3) & 3) * 128 + (quad * 4) * 8 + (col & 7);
  }

  const f32x4 zero4 = (f32x4){0.f, 0.f, 0.f, 0.f};
  u32 dzA[4], dRA[4], dnA[4], dzB[4], dRB[4], dnB[4];

  __syncthreads();

  GARU_LOADP(aa + (size_t)row0 * 768, dzA, dRA, dnA);   // st = 0

  for (int st2 = 0; st2 < 96; st2 += 2) {
    const u16* abB = aa + ((size_t)(st2 + 1) * 1024 + row0) * 768;
    GARU_LOADP(abB, dzB, dRB, dnB);
    GARU_STEP(dzA, dRA, dnA);
    if (st2 + 2 < 96) {
      const u16* abA = aa + ((size_t)(st2 + 2) * 1024 + row0) * 768;
      GARU_LOADP(abA, dzA, dRA, dnA);
    }
    GARU_STEP(dzB, dRB, dnB);
  }

  // classifier
  const float* W1 = wsf + OFF_W1;
  const float* B1 = wsf + OFF_B1;
  const float* W2 = wsf + OFF_W2;
  const float* B2 = wsf + OFF_B2;
#pragma unroll
  for (int rloc = 0; rloc < 2; rloc++) {
    int rr = w * 2 + rloc;
    float hid = B1[lane];
    for (int c = 0; c < 256; c++) {
      int addr = (c >> 5) * 512 + ((c >> 3) & 3) * 128 + rr * 8 + (c & 7);
      hid = fmaf(bf2f(shA[addr]), W1[c * 64 + lane], hid);
    }
    hid = fmaxf(hid, 0.f);
    float v = hid * W2[lane];
#pragma unroll
    for (int off = 32; off > 0; off >>= 1) v += __shfl_xor(v, off, 64);
    if (lane == 0) outp[row0 + rr] = sigm(v + B2[0]);
  }
}

// ============================ launch ============================
extern "C" void kernel_launch(void* const* d_in, const int* in_sizes, int n_in,
                              void* d_out, int out_size, void* d_ws, size_t ws_size,
                              hipStream_t stream) {
  const void* x    = d_in[0];
  const void* adj  = d_in[1];
  const void* wfi  = d_in[2];
  const void* wz   = d_in[4];
  const void* uz   = d_in[5];
  const void* bz   = d_in[6];
  const void* wr   = d_in[7];
  const void* ur   = d_in[8];
  const void* br   = d_in[9];
  const void* wh   = d_in[10];
  const void* uh   = d_in[11];
  const void* bh   = d_in[12];
  const void* wgp  = d_in[13];
  const void* bgp  = d_in[14];
  const void* wgz  = d_in[15];
  const void* ugz  = d_in[16];
  const void* bgz  = d_in[17];
  const void* wgr  = d_in[18];
  const void* ugr  = d_in[19];
  const void* bgr  = d_in[20];
  const void* wgn  = d_in[21];
  const void* ugn  = d_in[22];
  const void* bgn  = d_in[23];

  float* wsf  = (float*)d_ws;
  u16* ugpk   = (u16*)((char*)d_ws + UGPK_BYTE);
  u16* bpk2   = (u16*)((char*)d_ws + BPK2_BYTE);
  u16* bpk3   = (u16*)((char*)d_ws + BPK3_BYTE);
  u16* gnnpk  = (u16*)((char*)d_ws + GNNPK_BYTE);
  u16* gi     = (u16*)((char*)d_ws + GI_BYTE);
  u16* comb   = (u16*)((char*)d_ws + X_BYTE);   // X region: comb first...
  u16* aa     = (u16*)((char*)d_ws + X_BYTE);   // ...then aa overwrites (comb dead)

  k_detect<<<1, 256, 0, stream>>>((const u32*)x, wsf);

  k_convert<<<(WF_TOTAL + 255) / 256, 256, 0, stream>>>(
      wfi, d_in[3], wz, uz, bz, wr, ur, br, wh, uh, bh,
      wgp, bgp, wgz, bgz, wgr, bgr, wgn, bgn, d_in[24], d_in[25], d_in[26], d_in[27], wsf);

  k_pack_ug<<<(196608 + 255) / 256, 256, 0, stream>>>(ugz, ugr, ugn, wsf, ugpk);

  k_pack<<<(81920 + 196608 + 255) / 256, 256, 0, stream>>>(
      wgp, wgz, wgr, wgn, wsf, bpk2, bpk3);

  k_pack_gnn<<<100, 256, 0, stream>>>(wfi, wz, uz, wr, ur, wh, uh, wsf, gnnpk);

  // K1: all 98304 problems -> comb (X)
  k_gnn_mfma<<<TB_TOTAL / GP, 256, 0, stream>>>(x, adj, wsf, gnnpk, comb);

  // K2: gi = comb @ Wgp + bgp
  k_gemm_mfma<<<dim3(TB_TOTAL / 64, 1), 256, 0, stream>>>(
      comb, bpk2, wsf + OFF_BGP, gi, 320, 256);

  // K3: aa = gi @ [Wgz|Wgr|Wgn] + bgcat (writes X; comb dead)
  k_gemm_mfma<<<dim3(TB_TOTAL / 64, 3), 256, 0, stream>>>(
      gi, bpk3, wsf + OFF_BGCAT, aa, 256, 768);

  // K4: MFMA GARU v4 -> d_out (144 KB dynamic LDS)
  k_garu_mfma<<<64, 512, 147456, stream>>>(aa, ugpk, wsf, (float*)d_out);
}